// Round 19
// baseline (111.697 us; speedup 1.0000x reference)
//
#include <hip/hip_runtime.h>
#include <stdint.h>

#define NLVL 16
#define TSIZE 16384
#define HW 512

typedef float vfloat4 __attribute__((ext_vector_type(4)));  // native vec for nt-store

__constant__ int c_n[NLVL] = {16,20,25,32,40,50,64,80,101,128,161,203,256,322,406,512};

__device__ __forceinline__ uint32_t pkmax(uint32_t a, uint32_t b) {
    uint32_t r;
    asm("v_pk_max_u16 %0, %1, %2" : "=v"(r) : "v"(a), "v"(b));
    return r;
}

// One do_tile = one (level, batch, 32x32 output tile). LDS (17952 B):
//   V    [33][68] u32 : vertical window-max (stride 68 -> ~2-way banks)
//   feat [33][34] f2  : gathered features
// Two levels with adjacent K run back-to-back in ONE block: the 2nd level's
// x region overlaps the 1st's ~95% and is read immediately after -> L1 hits
// instead of L2 re-reads (L2 BW is the binding resource). No inter-level
// sync needed: A2's V writes come after the B1->C1 barrier (all threads
// done reading V); B2's feat writes come after A2's barrier (all done C1).
template<int K>
__device__ __forceinline__ void do_tile(
        const int lvl, const int b, const int tx0, const int ty0,
        const float* __restrict__ x, const float* __restrict__ table,
        float* __restrict__ out, uint32_t* lds) {
    constexpr int gh = 513 - K;
    constexpr float s = (float)gh * (1.0f / 512.0f);   // exact: gh * 2^-9
    const float nf = (float)c_n[lvl];
    const int tid = threadIdx.x;

    const float* xb0 = x + (size_t)b * 2 * HW * HW;
    const float* xb1 = xb0 + HW * HW;
    const float2* tb = (const float2*)table + (size_t)lvl * TSIZE;
    float* ob = out + ((size_t)b * 32 + lvl * 2) * HW * HW;

    uint32_t* V   = lds;                          // [33][68]
    float2*  feat = (float2*)(lds + 33 * 68);     // [33][34]

    const int gy_base = (int)floorf(((float)ty0 + 0.5f) * s - 0.5f);  // may be -1
    const int gx_base = (int)floorf(((float)tx0 + 0.5f) * s - 0.5f);
    const int rmin = max(gy_base, 0);
    const int cmin = max(gx_base, 0);

    // ---- phase A: global->reg load + vertical van Herk, lane = column ----
    {
        const int wv = __builtin_amdgcn_readfirstlane(tid >> 6);  // wave id -> SGPR
        const int c  = tid & 63;
        const int r0 = 8 * wv;
        const int xx = min(cmin + c, HW - 1);
        const int ybase = rmin + r0;
        uint32_t e[K + 8];
#pragma unroll
        for (int t = 0; t < K + 8; ++t) {
            const int yy = min(ybase + t, HW - 1);
            const float v0 = (xb0 + yy * HW)[xx];
            const float v1 = (xb1 + yy * HW)[xx];
            e[t] = (uint32_t)(v0 * nf) | ((uint32_t)(v1 * nf) << 16);
        }
        uint32_t o[9];
        if constexpr (K >= 10) {
            uint32_t sfx[9];
            sfx[8] = e[8];
#pragma unroll
            for (int t = 7; t >= 0; --t) sfx[t] = pkmax(e[t], sfx[t + 1]);
            uint32_t run = e[9];
#pragma unroll
            for (int m = 9; m <= K + 7; ++m) {
                if (m > 9) run = pkmax(run, e[m]);
                if (m >= K - 1) o[m - K + 1] = pkmax(sfx[m - K + 1], run);
            }
        } else {
#pragma unroll
            for (int i = 0; i < 9; ++i) {
                uint32_t m = e[i];
#pragma unroll
                for (int t = 1; t < K; ++t) m = pkmax(m, e[i + t]);
                o[i] = m;
            }
        }
        const int vb = r0 * 68 + c;
#pragma unroll
        for (int t = 0; t < 9; ++t) V[vb + t * 68] = o[t];
    }
    __syncthreads();

    // ---- phase B: horizontal van Herk + hash + direct gather ----
    if (tid < 99) {
        const int i = tid / 3, g = tid % 3;
        constexpr int NE  = 12 + K - 1;
        constexpr int NCH = (NE + 3) >> 2;
        uint32_t f[NCH * 4];
        const uint4* rp = (const uint4*)(V + i * 68 + 12 * g);   // 16B aligned
#pragma unroll
        for (int cc = 0; cc < NCH; ++cc) {
            const uint4 q = rp[cc];
            f[4*cc] = q.x; f[4*cc+1] = q.y; f[4*cc+2] = q.z; f[4*cc+3] = q.w;
        }
        uint32_t wm[12];
        if constexpr (K >= 13) {
            uint32_t sfx[12];
            sfx[11] = f[11];
#pragma unroll
            for (int d = 10; d >= 0; --d) sfx[d] = pkmax(f[d], sfx[d + 1]);
            uint32_t run = f[12];
#pragma unroll
            for (int m = 12; m <= K + 10; ++m) {
                if (m > 12) run = pkmax(run, f[m]);
                if (m >= K - 1) wm[m - K + 1] = pkmax(sfx[m - K + 1], run);
            }
        } else {
#pragma unroll
            for (int d = 0; d < 12; ++d) {
                uint32_t m = f[d];
#pragma unroll
                for (int t = 1; t < K; ++t) m = pkmax(m, f[d + t]);
                wm[d] = m;
            }
        }
#pragma unroll
        for (int d = 0; d < 12; ++d) {
            const int j = 12 * g + d;
            if (j < 33) {
                const uint32_t m = wm[d];
                const uint32_t idx = ((m & 0xFFFFu) ^ ((m >> 16) * 2654435761u)) & (TSIZE - 1);
                feat[i * 34 + j] = tb[idx];
            }
        }
    }
    __syncthreads();

    // ---- phase C: bilinear interp + nontemporal store ----
    const int bty = tid >> 5, btx = tid & 31;
    const int xo = tx0 + btx;
    const float sxf = ((float)xo + 0.5f) * s - 0.5f;
    const float fxf = floorf(sxf);
    const float wx = sxf - fxf;
    const int x0i = (int)fxf;
    const int jx0 = min(max(x0i, 0), gh - 1) - cmin;
    const int jx1 = min(max(x0i + 1, 0), gh - 1) - cmin;
    for (int oy = bty; oy < 32; oy += 8) {
        const int y = ty0 + oy;
        const float syf = ((float)y + 0.5f) * s - 0.5f;
        const float fyf = floorf(syf);
        const float wy = syf - fyf;
        const int y0i = (int)fyf;
        const int iy0 = min(max(y0i, 0), gh - 1) - rmin;
        const int iy1 = min(max(y0i + 1, 0), gh - 1) - rmin;
        const float2 f00 = feat[iy0 * 34 + jx0], f01 = feat[iy0 * 34 + jx1];
        const float2 f10 = feat[iy1 * 34 + jx0], f11 = feat[iy1 * 34 + jx1];
        const float w11 = wy * wx;
        const float w10 = wy - w11;
        const float w01 = wx - w11;
        const float w00 = 1.0f - wy - wx + w11;
        const float c0 = f00.x * w00 + f01.x * w01 + f10.x * w10 + f11.x * w11;
        const float c1 = f00.y * w00 + f01.y * w01 + f10.y * w10 + f11.y * w11;
        const size_t o = (size_t)y * HW + xo;
        __builtin_nontemporal_store(c0, &ob[o]);
        __builtin_nontemporal_store(c1, &ob[o + (size_t)HW * HW]);
    }
}

// Identity levels 13,14,15 (K=1, gh=512, s=1 -> bilinear is identity): one
// block loads x ONCE and produces all three levels' outputs (saves 2 of 3
// x read passes; the 2nd/3rd use registers, not even L1).
__device__ __forceinline__ void identity3(
        const int b, const int tx0, const int ty0,
        const float* __restrict__ x, const float* __restrict__ table,
        float* __restrict__ out) {
    const int tid = threadIdx.x;
    const int oy = tid >> 3, xo = tx0 + (tid & 7) * 4;
    const int y = ty0 + oy;
    const float* xb0 = x + (size_t)b * 2 * HW * HW;
    const float* xb1 = xb0 + HW * HW;
    const float4 v0 = *(const float4*)&xb0[y * HW + xo];
    const float4 v1 = *(const float4*)&xb1[y * HW + xo];
    const size_t o = (size_t)y * HW + xo;
#pragma unroll
    for (int li = 0; li < 3; ++li) {
        const int lvl = 13 + li;
        const float nf = (float)c_n[13 + li];          // 322, 406, 512 (exact)
        const float2* tb = (const float2*)table + (size_t)lvl * TSIZE;
        float* ob = out + ((size_t)b * 32 + lvl * 2) * HW * HW;
        const uint32_t i0 = (((uint32_t)(v0.x * nf)) ^ (((uint32_t)(v1.x * nf)) * 2654435761u)) & (TSIZE - 1);
        const uint32_t i1 = (((uint32_t)(v0.y * nf)) ^ (((uint32_t)(v1.y * nf)) * 2654435761u)) & (TSIZE - 1);
        const uint32_t i2 = (((uint32_t)(v0.z * nf)) ^ (((uint32_t)(v1.z * nf)) * 2654435761u)) & (TSIZE - 1);
        const uint32_t i3 = (((uint32_t)(v0.w * nf)) ^ (((uint32_t)(v1.w * nf)) * 2654435761u)) & (TSIZE - 1);
        const float2 f0 = tb[i0], f1 = tb[i1], f2 = tb[i2], f3 = tb[i3];
        const vfloat4 o0 = (vfloat4){f0.x, f1.x, f2.x, f3.x};
        const vfloat4 o1 = (vfloat4){f0.y, f1.y, f2.y, f3.y};
        __builtin_nontemporal_store(o0, (vfloat4*)&ob[o]);
        __builtin_nontemporal_store(o1, (vfloat4*)&ob[o + (size_t)HW * HW]);
    }
}

// Grid: bid = group*2048 + tile*8 + b. 8 groups x 256 tiles x 8 batches.
//   b fastest -> batch pinned to XCD (x slice + tables L2-resident).
//   Groups pair levels with adjacent K (heavy groups dispatch first; light
//   groups fill the scheduling tail).
__global__ __launch_bounds__(256) void fused_kernel(
        const float* __restrict__ x, const float* __restrict__ table,
        float* __restrict__ out) {
    __shared__ __align__(16) uint32_t lds[33 * 68 + 33 * 34 * 2];  // 17952 B

    const int bid  = blockIdx.x;
    const int b    = bid & 7;
    const int tile = (bid >> 3) & 255;
    const int grp  = bid >> 11;            // 0..7
    const int tx0  = (tile & 15) * 32;
    const int ty0  = (tile >> 4) * 32;

    switch (grp) {
        case 0: do_tile<32>( 0, b, tx0, ty0, x, table, out, lds);
                do_tile<25>( 1, b, tx0, ty0, x, table, out, lds); break;
        case 1: do_tile<20>( 2, b, tx0, ty0, x, table, out, lds);
                do_tile<16>( 3, b, tx0, ty0, x, table, out, lds); break;
        case 2: do_tile<12>( 4, b, tx0, ty0, x, table, out, lds);
                do_tile<10>( 5, b, tx0, ty0, x, table, out, lds); break;
        case 3: do_tile< 8>( 6, b, tx0, ty0, x, table, out, lds);
                do_tile< 6>( 7, b, tx0, ty0, x, table, out, lds); break;
        case 4: do_tile< 5>( 8, b, tx0, ty0, x, table, out, lds);
                do_tile< 4>( 9, b, tx0, ty0, x, table, out, lds); break;
        case 5: do_tile< 3>(10, b, tx0, ty0, x, table, out, lds);
                do_tile< 2>(11, b, tx0, ty0, x, table, out, lds); break;
        case 6: do_tile< 2>(12, b, tx0, ty0, x, table, out, lds); break;
        default: identity3(b, tx0, ty0, x, table, out); break;
    }
}

extern "C" void kernel_launch(void* const* d_in, const int* in_sizes, int n_in,
                              void* d_out, int out_size, void* d_ws, size_t ws_size,
                              hipStream_t stream) {
    const float* x     = (const float*)d_in[0];
    const float* table = (const float*)d_in[1];
    float* out         = (float*)d_out;
    (void)d_ws; (void)ws_size;

    fused_kernel<<<dim3(8 * 256 * 8), dim3(256), 0, stream>>>(x, table, out);
}

// Round 20
// 106.032 us; speedup vs baseline: 1.0534x; 1.0534x over previous
//
#include <hip/hip_runtime.h>
#include <stdint.h>

#define NLVL 16
#define TSIZE 16384
#define HW 512

typedef float vfloat4 __attribute__((ext_vector_type(4)));  // native vec for nt-store

__constant__ int c_n[NLVL] = {16,20,25,32,40,50,64,80,101,128,161,203,256,322,406,512};

__device__ __forceinline__ uint32_t pkmax(uint32_t a, uint32_t b) {
    uint32_t r;
    asm("v_pk_max_u16 %0, %1, %2" : "=v"(r) : "v"(a), "v"(b));
    return r;
}

// P sliding-window (width KK) maxima over e[0..P+KK-2]: o[j] = max(e[j..j+KK-1]).
// Van Herk (suffix+run) when KK > P, direct unroll otherwise. All indices static.
template<int KK, int P, int NE>
__device__ __forceinline__ void winmaxNU(const uint32_t (&e)[NE], uint32_t (&o)[P]) {
    static_assert(NE >= P + KK - 1, "window overrun");
    if constexpr (KK > P) {
        uint32_t sfx[P];
        sfx[P - 1] = e[P - 1];
#pragma unroll
        for (int t = P - 2; t >= 0; --t) sfx[t] = pkmax(e[t], sfx[t + 1]);
        uint32_t run = e[P];
#pragma unroll
        for (int m = P; m <= P + KK - 2; ++m) {
            if (m > P) run = pkmax(run, e[m]);
            const int j = m - KK + 1;
            if (j >= 0 && j < P) o[j] = pkmax(sfx[j], run);
        }
    } else {
#pragma unroll
        for (int i = 0; i < P; ++i) {
            uint32_t m = e[i];
#pragma unroll
            for (int t = 1; t < KK; ++t) m = pkmax(m, e[i + t]);
            o[i] = m;
        }
    }
}

// Horizontal window-max + hash + gather: V[33][68] packed -> feat[33][34].
template<int K>
__device__ __forceinline__ void phaseB(const uint32_t* __restrict__ V,
                                       float2* __restrict__ feat,
                                       const float2* __restrict__ tb, const int tid) {
    if (tid < 99) {
        const int i = tid / 3, g = tid % 3;
        constexpr int NE  = 12 + K - 1;
        constexpr int NCH = (NE + 3) >> 2;
        uint32_t f[NCH * 4];
        const uint4* rp = (const uint4*)(V + i * 68 + 12 * g);   // 16B aligned
#pragma unroll
        for (int cc = 0; cc < NCH; ++cc) {
            const uint4 q = rp[cc];
            f[4*cc] = q.x; f[4*cc+1] = q.y; f[4*cc+2] = q.z; f[4*cc+3] = q.w;
        }
        uint32_t wm[12];
        winmaxNU<K, 12, NCH * 4>(f, wm);
#pragma unroll
        for (int d = 0; d < 12; ++d) {
            const int j = 12 * g + d;
            if (j < 33) {
                const uint32_t m = wm[d];
                const uint32_t idx = ((m & 0xFFFFu) ^ ((m >> 16) * 2654435761u)) & (TSIZE - 1);
                feat[i * 34 + j] = tb[idx];
            }
        }
    }
}

// Bilinear interp from feat + nt stores.
template<int K>
__device__ __forceinline__ void phaseC(const float2* __restrict__ feat,
                                       float* __restrict__ ob,
                                       const int rmin, const int cmin,
                                       const int tx0, const int ty0, const int tid) {
    constexpr int gh = 513 - K;
    constexpr float s = (float)gh * (1.0f / 512.0f);
    const int bty = tid >> 5, btx = tid & 31;
    const int xo = tx0 + btx;
    const float sxf = ((float)xo + 0.5f) * s - 0.5f;
    const float fxf = floorf(sxf);
    const float wx = sxf - fxf;
    const int x0i = (int)fxf;
    const int jx0 = min(max(x0i, 0), gh - 1) - cmin;
    const int jx1 = min(max(x0i + 1, 0), gh - 1) - cmin;
    for (int oy = bty; oy < 32; oy += 8) {
        const int y = ty0 + oy;
        const float syf = ((float)y + 0.5f) * s - 0.5f;
        const float fyf = floorf(syf);
        const float wy = syf - fyf;
        const int y0i = (int)fyf;
        const int iy0 = min(max(y0i, 0), gh - 1) - rmin;
        const int iy1 = min(max(y0i + 1, 0), gh - 1) - rmin;
        const float2 f00 = feat[iy0 * 34 + jx0], f01 = feat[iy0 * 34 + jx1];
        const float2 f10 = feat[iy1 * 34 + jx0], f11 = feat[iy1 * 34 + jx1];
        const float w11 = wy * wx;
        const float w10 = wy - w11;
        const float w01 = wx - w11;
        const float w00 = 1.0f - wy - wx + w11;
        const float c0 = f00.x * w00 + f01.x * w01 + f10.x * w10 + f11.x * w11;
        const float c1 = f00.y * w00 + f01.y * w01 + f10.y * w10 + f11.y * w11;
        const size_t o = (size_t)y * HW + xo;
        __builtin_nontemporal_store(c0, &ob[o]);
        __builtin_nontemporal_store(c1, &ob[o + (size_t)HW * HW]);
    }
}

// TWO levels (K1 > K2) from ONE loaded register strip: the x rows are loaded
// once and packed twice (per-level nf) -> phase-A load requests HALVE.
// Level-2's grid shift (dr,dc in [0,K1-K2]) is absorbed by computing all
// K1-K2+9 window starts (compile-time) and writing LDS at shifted positions.
template<int K1, int K2>
__device__ __forceinline__ void do_pair(
        const int l1, const int l2, const int b, const int tx0, const int ty0,
        const float* __restrict__ x, const float* __restrict__ table,
        float* __restrict__ out, uint32_t* lds) {
    constexpr float s1 = (float)(513 - K1) * (1.0f / 512.0f);
    constexpr float s2 = (float)(513 - K2) * (1.0f / 512.0f);
    const float nf1 = (float)c_n[l1], nf2 = (float)c_n[l2];
    const int tid = threadIdx.x;

    const float* xb0 = x + (size_t)b * 2 * HW * HW;
    const float* xb1 = xb0 + HW * HW;

    uint32_t* V1  = lds;                           // [33][68]
    uint32_t* V2  = lds + 2244;                    // [33][68]
    float2*  feat = (float2*)(lds + 4488);         // [33][34]

    const int rmin1 = max((int)floorf(((float)ty0 + 0.5f) * s1 - 0.5f), 0);
    const int cmin1 = max((int)floorf(((float)tx0 + 0.5f) * s1 - 0.5f), 0);
    const int rmin2 = max((int)floorf(((float)ty0 + 0.5f) * s2 - 0.5f), 0);
    const int cmin2 = max((int)floorf(((float)tx0 + 0.5f) * s2 - 0.5f), 0);
    const int dr = rmin2 - rmin1;                  // in [0, K1-K2]
    const int dc = cmin2 - cmin1;                  // in [0, K1-K2]

    // ---- phase A: load ONCE, pack per level, dual vertical van Herk ----
    {
        const int wv = __builtin_amdgcn_readfirstlane(tid >> 6);
        const int c  = tid & 63;
        const int r0 = 8 * wv;
        const int xx = min(cmin1 + c, HW - 1);
        const int ybase = rmin1 + r0;
        uint32_t eA[K1 + 8], eB[K1 + 8];
#pragma unroll
        for (int t = 0; t < K1 + 8; ++t) {
            const int yy = min(ybase + t, HW - 1);
            const float v0 = (xb0 + yy * HW)[xx];
            const float v1 = (xb1 + yy * HW)[xx];
            eA[t] = (uint32_t)(v0 * nf1) | ((uint32_t)(v1 * nf1) << 16);
            eB[t] = (uint32_t)(v0 * nf2) | ((uint32_t)(v1 * nf2) << 16);
        }
        uint32_t o1[9];
        winmaxNU<K1, 9, K1 + 8>(eA, o1);
        const int vb = r0 * 68 + c;
#pragma unroll
        for (int t = 0; t < 9; ++t) V1[vb + t * 68] = o1[t];

        constexpr int P2 = K1 - K2 + 9;
        uint32_t o2[P2];
        winmaxNU<K2, P2, K1 + 8>(eB, o2);
        const int c2 = c - dc;                     // shifted col (dynamic, LDS ok)
#pragma unroll
        for (int j = 0; j < P2; ++j) {
            const int i2 = r0 + j - dr;            // shifted row
            if (i2 >= 0 && i2 <= 32 && c2 >= 0)
                V2[i2 * 68 + c2] = o2[j];          // dup rows across waves: same value
        }
    }
    __syncthreads();

    phaseB<K1>(V1, feat, (const float2*)table + (size_t)l1 * TSIZE, tid);
    __syncthreads();
    phaseC<K1>(feat, out + ((size_t)b * 32 + l1 * 2) * HW * HW, rmin1, cmin1, tx0, ty0, tid);
    __syncthreads();
    phaseB<K2>(V2, feat, (const float2*)table + (size_t)l2 * TSIZE, tid);
    __syncthreads();
    phaseC<K2>(feat, out + ((size_t)b * 32 + l2 * 2) * HW * HW, rmin2, cmin2, tx0, ty0, tid);
}

// Single level (group 6): R12 structure via the shared phase helpers.
template<int K>
__device__ __forceinline__ void do_tile(
        const int lvl, const int b, const int tx0, const int ty0,
        const float* __restrict__ x, const float* __restrict__ table,
        float* __restrict__ out, uint32_t* lds) {
    constexpr float s = (float)(513 - K) * (1.0f / 512.0f);
    const float nf = (float)c_n[lvl];
    const int tid = threadIdx.x;
    const float* xb0 = x + (size_t)b * 2 * HW * HW;
    const float* xb1 = xb0 + HW * HW;
    uint32_t* V   = lds;
    float2*  feat = (float2*)(lds + 2244);

    const int rmin = max((int)floorf(((float)ty0 + 0.5f) * s - 0.5f), 0);
    const int cmin = max((int)floorf(((float)tx0 + 0.5f) * s - 0.5f), 0);
    {
        const int wv = __builtin_amdgcn_readfirstlane(tid >> 6);
        const int c  = tid & 63;
        const int r0 = 8 * wv;
        const int xx = min(cmin + c, HW - 1);
        const int ybase = rmin + r0;
        uint32_t e[K + 8];
#pragma unroll
        for (int t = 0; t < K + 8; ++t) {
            const int yy = min(ybase + t, HW - 1);
            const float v0 = (xb0 + yy * HW)[xx];
            const float v1 = (xb1 + yy * HW)[xx];
            e[t] = (uint32_t)(v0 * nf) | ((uint32_t)(v1 * nf) << 16);
        }
        uint32_t o[9];
        winmaxNU<K, 9, K + 8>(e, o);
        const int vb = r0 * 68 + c;
#pragma unroll
        for (int t = 0; t < 9; ++t) V[vb + t * 68] = o[t];
    }
    __syncthreads();
    phaseB<K>(V, feat, (const float2*)table + (size_t)lvl * TSIZE, tid);
    __syncthreads();
    phaseC<K>(feat, out + ((size_t)b * 32 + lvl * 2) * HW * HW, rmin, cmin, tx0, ty0, tid);
}

// Identity levels 13,14,15 (K=1, s=1 -> bilinear is identity): x loaded once.
__device__ __forceinline__ void identity3(
        const int b, const int tx0, const int ty0,
        const float* __restrict__ x, const float* __restrict__ table,
        float* __restrict__ out) {
    const int tid = threadIdx.x;
    const int oy = tid >> 3, xo = tx0 + (tid & 7) * 4;
    const int y = ty0 + oy;
    const float* xb0 = x + (size_t)b * 2 * HW * HW;
    const float* xb1 = xb0 + HW * HW;
    const float4 v0 = *(const float4*)&xb0[y * HW + xo];
    const float4 v1 = *(const float4*)&xb1[y * HW + xo];
    const size_t o = (size_t)y * HW + xo;
#pragma unroll
    for (int li = 0; li < 3; ++li) {
        const int lvl = 13 + li;
        const float nf = (float)c_n[13 + li];
        const float2* tb = (const float2*)table + (size_t)lvl * TSIZE;
        float* ob = out + ((size_t)b * 32 + lvl * 2) * HW * HW;
        const uint32_t i0 = (((uint32_t)(v0.x * nf)) ^ (((uint32_t)(v1.x * nf)) * 2654435761u)) & (TSIZE - 1);
        const uint32_t i1 = (((uint32_t)(v0.y * nf)) ^ (((uint32_t)(v1.y * nf)) * 2654435761u)) & (TSIZE - 1);
        const uint32_t i2 = (((uint32_t)(v0.z * nf)) ^ (((uint32_t)(v1.z * nf)) * 2654435761u)) & (TSIZE - 1);
        const uint32_t i3 = (((uint32_t)(v0.w * nf)) ^ (((uint32_t)(v1.w * nf)) * 2654435761u)) & (TSIZE - 1);
        const float2 f0 = tb[i0], f1 = tb[i1], f2 = tb[i2], f3 = tb[i3];
        const vfloat4 o0 = (vfloat4){f0.x, f1.x, f2.x, f3.x};
        const vfloat4 o1 = (vfloat4){f0.y, f1.y, f2.y, f3.y};
        __builtin_nontemporal_store(o0, (vfloat4*)&ob[o]);
        __builtin_nontemporal_store(o1, (vfloat4*)&ob[o + (size_t)HW * HW]);
    }
}

// Grid: bid = group*2048 + tile*8 + b (b fastest -> batch pinned to XCD;
// heavy pair-groups dispatch first, identity fills the tail).
__global__ __launch_bounds__(256) void fused_kernel(
        const float* __restrict__ x, const float* __restrict__ table,
        float* __restrict__ out) {
    __shared__ __align__(16) uint32_t lds[6732];   // 26928 B (V1+V2+feat)

    const int bid  = blockIdx.x;
    const int b    = bid & 7;
    const int tile = (bid >> 3) & 255;
    const int grp  = bid >> 11;            // 0..7
    const int tx0  = (tile & 15) * 32;
    const int ty0  = (tile >> 4) * 32;

    switch (grp) {
        case 0: do_pair<32,25>( 0,  1, b, tx0, ty0, x, table, out, lds); break;
        case 1: do_pair<20,16>( 2,  3, b, tx0, ty0, x, table, out, lds); break;
        case 2: do_pair<12,10>( 4,  5, b, tx0, ty0, x, table, out, lds); break;
        case 3: do_pair< 8, 6>( 6,  7, b, tx0, ty0, x, table, out, lds); break;
        case 4: do_pair< 5, 4>( 8,  9, b, tx0, ty0, x, table, out, lds); break;
        case 5: do_pair< 3, 2>(10, 11, b, tx0, ty0, x, table, out, lds); break;
        case 6: do_tile< 2>(12, b, tx0, ty0, x, table, out, lds); break;
        default: identity3(b, tx0, ty0, x, table, out); break;
    }
}

extern "C" void kernel_launch(void* const* d_in, const int* in_sizes, int n_in,
                              void* d_out, int out_size, void* d_ws, size_t ws_size,
                              hipStream_t stream) {
    const float* x     = (const float*)d_in[0];
    const float* table = (const float*)d_in[1];
    float* out         = (float*)d_out;
    (void)d_ws; (void)ws_size;

    fused_kernel<<<dim3(8 * 256 * 8), dim3(256), 0, stream>>>(x, table, out);
}